// Round 3
// baseline (332.771 us; speedup 1.0000x reference)
//
#include <hip/hip_runtime.h>

// BalancedBCEWithLogitsLoss, MI355X (gfx950).  Round 3.
//
// loss = (sum_pos_bce + K * sum_neg_bce / num_neg) / (num_pos + K),
// K = max(3*num_pos, floor(0.05*n)).  (Population-mean substitution for the
// reference's random negative sample — verified absmax 0.0 in R1/R2.)
//
// R2 post-mortem: grid-stride unroll-2 was latency-bound (VALUBusy 8.5%,
// HBM 5.8%, 0.92 TB/s effective).  R3: straight-line copy-shaped kernel —
// block-contiguous, 8 float4 loads issued back-to-back per thread (128 B/lane
// in flight), y∈{0,1} identity (pos_sum = Σ y·bce) to kill cndmask chains.

__global__ __launch_bounds__(256) void bce_kernel(
    const float* __restrict__ pred,
    const float* __restrict__ label,
    float*       __restrict__ sums,   // ws: [0]=pos_sum [1]=total_sum [2]=pos_cnt
    unsigned*    __restrict__ done,   // ws: blocks-finished counter
    float*       __restrict__ out,
    int n, int nblocks)
{
    const int n4 = n >> 2;
    const float4* __restrict__ p4 = (const float4*)pred;
    const float4* __restrict__ y4 = (const float4*)label;

    // block-contiguous: block b owns float4 range [b*1024, b*1024+1024)
    const int base = blockIdx.x * 1024 + threadIdx.x;
    const int i0 = base, i1 = base + 256, i2 = base + 512, i3 = base + 768;

    const float4 zero4 = make_float4(0.f, 0.f, 0.f, 0.f);
    // 8 loads issued straight-line before any use
    float4 x0 = (i0 < n4) ? p4[i0] : zero4;
    float4 x1 = (i1 < n4) ? p4[i1] : zero4;
    float4 x2 = (i2 < n4) ? p4[i2] : zero4;
    float4 x3 = (i3 < n4) ? p4[i3] : zero4;
    float4 l0 = (i0 < n4) ? y4[i0] : zero4;
    float4 l1 = (i1 < n4) ? y4[i1] : zero4;
    float4 l2 = (i2 < n4) ? y4[i2] : zero4;
    float4 l3 = (i3 < n4) ? y4[i3] : zero4;
    // guard values: x=0,y=0 gives bce=log(2) — mask it below
    const float m0 = (i0 < n4) ? 1.f : 0.f;
    const float m1 = (i1 < n4) ? 1.f : 0.f;
    const float m2 = (i2 < n4) ? 1.f : 0.f;
    const float m3 = (i3 < n4) ? 1.f : 0.f;

    float tsum = 0.f;   // Σ bce (all elements)
    float psum = 0.f;   // Σ y * bce  (y ∈ {0,1})
    float csum = 0.f;   // Σ y        (num_pos, exact in fp32: partials ≤ 16)

    float xs[16] = {x0.x, x0.y, x0.z, x0.w, x1.x, x1.y, x1.z, x1.w,
                    x2.x, x2.y, x2.z, x2.w, x3.x, x3.y, x3.z, x3.w};
    float ys[16] = {l0.x, l0.y, l0.z, l0.w, l1.x, l1.y, l1.z, l1.w,
                    l2.x, l2.y, l2.z, l2.w, l3.x, l3.y, l3.z, l3.w};
    float ms[16] = {m0, m0, m0, m0, m1, m1, m1, m1,
                    m2, m2, m2, m2, m3, m3, m3, m3};
#pragma unroll
    for (int j = 0; j < 16; ++j) {
        float xi = xs[j], yi = ys[j];
        // stable BCE: max(x,0) - x*y + log(1+exp(-|x|)), HW v_exp/v_log
        float bce = fmaxf(xi, 0.f) - xi * yi
                  + __logf(1.f + __expf(-fabsf(xi)));
        bce *= ms[j];
        tsum += bce;
        psum = fmaf(yi, bce, psum);
        csum += yi;   // guard lanes have yi=0
    }

    // wave-64 reduce
#pragma unroll
    for (int off = 32; off > 0; off >>= 1) {
        tsum += __shfl_down(tsum, off);
        psum += __shfl_down(psum, off);
        csum += __shfl_down(csum, off);
    }

    __shared__ float st[4], sp[4], sc[4];
    __shared__ bool  isLast;
    const int wave = threadIdx.x >> 6;
    const int lane = threadIdx.x & 63;
    if (lane == 0) { st[wave] = tsum; sp[wave] = psum; sc[wave] = csum; }
    __syncthreads();

    if (threadIdx.x == 0) {
        atomicAdd(&sums[0], sp[0] + sp[1] + sp[2] + sp[3]);
        atomicAdd(&sums[1], st[0] + st[1] + st[2] + st[3]);
        atomicAdd(&sums[2], sc[0] + sc[1] + sc[2] + sc[3]);
        __threadfence();
        unsigned prev = atomicAdd(done, 1u);
        isLast = (prev == (unsigned)(nblocks - 1));
    }
    __syncthreads();

    if (isLast && threadIdx.x == 0) {
        // device-coherent reads (cross-XCD safe) via identity RMW
        double pos_sum = (double)atomicAdd(&sums[0], 0.f);
        double tot_sum = (double)atomicAdd(&sums[1], 0.f);
        double cntf    = (double)atomicAdd(&sums[2], 0.f);

        // scalar tail n4*4..n (dead when n % 4 == 0)
        for (int r = (n4 << 2); r < n; ++r) {
            float xi = pred[r], yi = label[r];
            float bce = fmaxf(xi, 0.f) - xi * yi
                      + __logf(1.f + __expf(-fabsf(xi)));
            tot_sum += bce;
            pos_sum += (double)yi * bce;
            cntf    += yi;
        }

        long long num_pos = (long long)(cntf + 0.5);
        long long num_neg = (long long)n - num_pos;
        long long least   = (long long)((double)n * 0.05);  // int(n*LEAST_NEG_PERCENT)
        long long K = 3LL * num_pos;
        if (K < least)   K = least;
        if (K > num_neg) K = num_neg;

        double neg_sum = tot_sum - pos_sum;
        double sel = (num_neg > 0) ? ((double)K * neg_sum / (double)num_neg) : 0.0;
        double denom = (double)num_pos + (double)K;
        out[0] = (float)((denom > 0.0) ? ((pos_sum + sel) / denom) : 0.0);
    }
}

extern "C" void kernel_launch(void* const* d_in, const int* in_sizes, int n_in,
                              void* d_out, int out_size, void* d_ws, size_t ws_size,
                              hipStream_t stream)
{
    const float* pred  = (const float*)d_in[0];
    const float* label = (const float*)d_in[1];
    const int n = in_sizes[0];

    float*    sums = (float*)d_ws;                 // 3 floats
    unsigned* done = (unsigned*)((char*)d_ws + 12);

    // ws is re-poisoned to 0xAA before every timed launch — zero our 16 bytes.
    hipMemsetAsync(d_ws, 0, 16, stream);

    // each block covers 1024 float4 = 4096 elements of each array
    const int blocks = (n + 4095) / 4096;          // 4096 for n = 16.78M
    bce_kernel<<<blocks, 256, 0, stream>>>(pred, label, sums, done,
                                           (float*)d_out, n, blocks);
}

// Round 4
// 147.988 us; speedup vs baseline: 2.2486x; 2.2486x over previous
//
#include <hip/hip_runtime.h>

// BalancedBCEWithLogitsLoss, MI355X (gfx950).  Round 4.
//
// loss = (sum_pos_bce + K * sum_neg_bce / num_neg) / (num_pos + K),
// K = max(3*num_pos, floor(0.05*n)), clamped to num_neg.
// (Population-mean substitution for the reference's random negative sample —
// verified absmax 0.0 in R1-R3.)
//
// R3 post-mortem: ALL previous rounds were bound by same-address device-scope
// atomics (~15 ns each, serialized cross-XCD): duration tracked atomic count
// linearly (6K->92us, 8K->123us, 16K->245us predicted vs 98/145/235 measured)
// while VALU (5.5%) and HBM (3.6%) pipes sat idle.  R4: ZERO atomics —
// per-block partials to distinct addresses via plain stores, second tiny
// kernel reduces 1024x3 floats and computes the closed form.  No memset.

#define NB_THREADS 256

__global__ __launch_bounds__(256) void bce_partial_kernel(
    const float* __restrict__ pred,
    const float* __restrict__ label,
    float*       __restrict__ part,   // [3*nblocks]: pos | tot | cnt
    int n4, int nblocks)
{
    const float4* __restrict__ p4 = (const float4*)pred;
    const float4* __restrict__ y4 = (const float4*)label;

    // block-contiguous: block b owns float4 range [b*4096, b*4096+4096)
    const int base = blockIdx.x * 4096 + threadIdx.x;
    const float4 zero4 = make_float4(0.f, 0.f, 0.f, 0.f);

    float tsum = 0.f;   // sum of bce over all elements
    float psum = 0.f;   // sum of y * bce   (y in {0,1})
    float csum = 0.f;   // sum of y         (num_pos; exact in fp32 here)

#pragma unroll
    for (int s = 0; s < 4; ++s) {
        const int i0 = base + s * 1024;
        const int i1 = i0 + 256, i2 = i0 + 512, i3 = i0 + 768;
        // 8 independent 16B loads issued before any use
        float4 x0 = (i0 < n4) ? p4[i0] : zero4;
        float4 x1 = (i1 < n4) ? p4[i1] : zero4;
        float4 x2 = (i2 < n4) ? p4[i2] : zero4;
        float4 x3 = (i3 < n4) ? p4[i3] : zero4;
        float4 l0 = (i0 < n4) ? y4[i0] : zero4;
        float4 l1 = (i1 < n4) ? y4[i1] : zero4;
        float4 l2 = (i2 < n4) ? y4[i2] : zero4;
        float4 l3 = (i3 < n4) ? y4[i3] : zero4;
        // guard lanes give x=0,y=0 -> bce=log(2); mask them out
        const float m0 = (i0 < n4) ? 1.f : 0.f;
        const float m1 = (i1 < n4) ? 1.f : 0.f;
        const float m2 = (i2 < n4) ? 1.f : 0.f;
        const float m3 = (i3 < n4) ? 1.f : 0.f;

        float xs[16] = {x0.x, x0.y, x0.z, x0.w, x1.x, x1.y, x1.z, x1.w,
                        x2.x, x2.y, x2.z, x2.w, x3.x, x3.y, x3.z, x3.w};
        float ys[16] = {l0.x, l0.y, l0.z, l0.w, l1.x, l1.y, l1.z, l1.w,
                        l2.x, l2.y, l2.z, l2.w, l3.x, l3.y, l3.z, l3.w};
        float ms[16] = {m0, m0, m0, m0, m1, m1, m1, m1,
                        m2, m2, m2, m2, m3, m3, m3, m3};
#pragma unroll
        for (int j = 0; j < 16; ++j) {
            float xi = xs[j], yi = ys[j];
            // stable BCE: max(x,0) - x*y + log(1+exp(-|x|)), HW v_exp/v_log
            float bce = fmaxf(xi, 0.f) - xi * yi
                      + __logf(1.f + __expf(-fabsf(xi)));
            bce *= ms[j];
            tsum += bce;
            psum = fmaf(yi, bce, psum);
            csum += yi;
        }
    }

    // wave-64 reduce
#pragma unroll
    for (int off = 32; off > 0; off >>= 1) {
        tsum += __shfl_down(tsum, off);
        psum += __shfl_down(psum, off);
        csum += __shfl_down(csum, off);
    }

    __shared__ float st[4], sp[4], sc[4];
    const int wave = threadIdx.x >> 6;
    const int lane = threadIdx.x & 63;
    if (lane == 0) { st[wave] = tsum; sp[wave] = psum; sc[wave] = csum; }
    __syncthreads();

    if (threadIdx.x == 0) {
        // plain stores to distinct addresses — no contention, no atomics
        part[blockIdx.x]               = sp[0] + sp[1] + sp[2] + sp[3];
        part[nblocks + blockIdx.x]     = st[0] + st[1] + st[2] + st[3];
        part[2 * nblocks + blockIdx.x] = sc[0] + sc[1] + sc[2] + sc[3];
    }
}

__global__ __launch_bounds__(256) void bce_final_kernel(
    const float* __restrict__ part, int nblocks,
    const float* __restrict__ pred, const float* __restrict__ label,
    int n, float* __restrict__ out)
{
    float psum = 0.f, tsum = 0.f, csum = 0.f;
    for (int i = threadIdx.x; i < nblocks; i += NB_THREADS) {
        psum += part[i];
        tsum += part[nblocks + i];
        csum += part[2 * nblocks + i];
    }
#pragma unroll
    for (int off = 32; off > 0; off >>= 1) {
        psum += __shfl_down(psum, off);
        tsum += __shfl_down(tsum, off);
        csum += __shfl_down(csum, off);
    }
    __shared__ float st[4], sp[4], sc[4];
    const int wave = threadIdx.x >> 6;
    const int lane = threadIdx.x & 63;
    if (lane == 0) { st[wave] = tsum; sp[wave] = psum; sc[wave] = csum; }
    __syncthreads();

    if (threadIdx.x == 0) {
        double pos_sum = (double)(sp[0] + sp[1] + sp[2] + sp[3]);
        double tot_sum = (double)(st[0] + st[1] + st[2] + st[3]);
        double cntf    = (double)(sc[0] + sc[1] + sc[2] + sc[3]);

        // scalar tail (n % 4 != 0) — dead for n = 16M
        const int n4 = n >> 2;
        for (int r = (n4 << 2); r < n; ++r) {
            float xi = pred[r], yi = label[r];
            float bce = fmaxf(xi, 0.f) - xi * yi
                      + __logf(1.f + __expf(-fabsf(xi)));
            tot_sum += bce;
            pos_sum += (double)yi * bce;
            cntf    += yi;
        }

        long long num_pos = (long long)(cntf + 0.5);
        long long num_neg = (long long)n - num_pos;
        long long least   = (long long)((double)n * 0.05); // int(n*0.05)
        long long K = 3LL * num_pos;
        if (K < least)   K = least;
        if (K > num_neg) K = num_neg;

        double neg_sum = tot_sum - pos_sum;
        double sel = (num_neg > 0) ? ((double)K * neg_sum / (double)num_neg) : 0.0;
        double denom = (double)num_pos + (double)K;
        out[0] = (float)((denom > 0.0) ? ((pos_sum + sel) / denom) : 0.0);
    }
}

extern "C" void kernel_launch(void* const* d_in, const int* in_sizes, int n_in,
                              void* d_out, int out_size, void* d_ws, size_t ws_size,
                              hipStream_t stream)
{
    const float* pred  = (const float*)d_in[0];
    const float* label = (const float*)d_in[1];
    const int n = in_sizes[0];
    const int n4 = n >> 2;

    // each block covers 4096 float4 = 16384 elements of each array
    int nblocks = (n4 + 4095) / 4096;
    if (nblocks < 1) nblocks = 1;                  // tiny-n safety

    float* part = (float*)d_ws;                    // 3 * nblocks floats

    bce_partial_kernel<<<nblocks, NB_THREADS, 0, stream>>>(pred, label, part,
                                                           n4, nblocks);
    bce_final_kernel<<<1, NB_THREADS, 0, stream>>>(part, nblocks, pred, label,
                                                   n, (float*)d_out);
}

// Round 5
// 145.428 us; speedup vs baseline: 2.2882x; 1.0176x over previous
//
#include <hip/hip_runtime.h>

// BalancedBCEWithLogitsLoss, MI355X (gfx950).  Round 5.
//
// loss = (sum_pos_bce + K * sum_neg_bce / num_neg) / (num_pos + K),
// K = max(3*num_pos, floor(0.05*n)), clamped to num_neg.
// (Population-mean substitution for the reference's random negative sample —
// verified absmax 0.0 in R1-R4.)
//
// R4 post-mortem: zero-atomic restructure confirmed the atomic-serialization
// theory (235 -> 45 us hot kernel).  Remaining 45 us vs ~11 us memory floor /
// ~10 us VALU floor = overlap deficit: 1024 blocks = 4/CU, 4 serialized
// load->wait->compute steps per wave, Occupancy 22%.  R5: 4096 blocks
// (16/CU, fills all 32 wave slots), ONE straight-line step per thread
// (8 x 16B loads back-to-back), uniform-branch full-block fast path (no
// guards, no mask ops).  Still zero atomics, zero memset.

#define NB_THREADS 256

__global__ __launch_bounds__(256) void bce_partial_kernel(
    const float* __restrict__ pred,
    const float* __restrict__ label,
    float*       __restrict__ part,   // [3*nblocks]: pos | tot | cnt
    int n4, int nblocks)
{
    const float4* __restrict__ p4 = (const float4*)pred;
    const float4* __restrict__ y4 = (const float4*)label;

    // block b owns float4 range [b*1024, (b+1)*1024)  (4096 elements)
    const int base = blockIdx.x * 1024 + threadIdx.x;
    const int i0 = base, i1 = base + 256, i2 = base + 512, i3 = base + 768;

    float4 x0, x1, x2, x3, l0, l1, l2, l3;
    float m0 = 1.f, m1 = 1.f, m2 = 1.f, m3 = 1.f;

    if ((blockIdx.x + 1) * 1024 <= n4) {
        // fast path (uniform branch): all 8 loads unguarded, back-to-back
        x0 = p4[i0]; x1 = p4[i1]; x2 = p4[i2]; x3 = p4[i3];
        l0 = y4[i0]; l1 = y4[i1]; l2 = y4[i2]; l3 = y4[i3];
    } else {
        const float4 zero4 = make_float4(0.f, 0.f, 0.f, 0.f);
        x0 = (i0 < n4) ? p4[i0] : zero4;
        x1 = (i1 < n4) ? p4[i1] : zero4;
        x2 = (i2 < n4) ? p4[i2] : zero4;
        x3 = (i3 < n4) ? p4[i3] : zero4;
        l0 = (i0 < n4) ? y4[i0] : zero4;
        l1 = (i1 < n4) ? y4[i1] : zero4;
        l2 = (i2 < n4) ? y4[i2] : zero4;
        l3 = (i3 < n4) ? y4[i3] : zero4;
        // guard lanes give x=0,y=0 -> bce=log(2); mask them out
        m0 = (i0 < n4) ? 1.f : 0.f;
        m1 = (i1 < n4) ? 1.f : 0.f;
        m2 = (i2 < n4) ? 1.f : 0.f;
        m3 = (i3 < n4) ? 1.f : 0.f;
    }

    float tsum = 0.f;   // sum of bce over all elements
    float psum = 0.f;   // sum of y * bce   (y in {0,1})
    float csum = 0.f;   // sum of y         (num_pos; exact in fp32 here)

    float xs[16] = {x0.x, x0.y, x0.z, x0.w, x1.x, x1.y, x1.z, x1.w,
                    x2.x, x2.y, x2.z, x2.w, x3.x, x3.y, x3.z, x3.w};
    float ys[16] = {l0.x, l0.y, l0.z, l0.w, l1.x, l1.y, l1.z, l1.w,
                    l2.x, l2.y, l2.z, l2.w, l3.x, l3.y, l3.z, l3.w};
    float ms[16] = {m0, m0, m0, m0, m1, m1, m1, m1,
                    m2, m2, m2, m2, m3, m3, m3, m3};
#pragma unroll
    for (int j = 0; j < 16; ++j) {
        float xi = xs[j], yi = ys[j];
        // stable BCE: max(x,0) - x*y + log(1+exp(-|x|)), HW v_exp/v_log
        float bce = fmaxf(xi, 0.f) - xi * yi
                  + __logf(1.f + __expf(-fabsf(xi)));
        bce *= ms[j];
        tsum += bce;
        psum = fmaf(yi, bce, psum);
        csum += yi;
    }

    // wave-64 reduce
#pragma unroll
    for (int off = 32; off > 0; off >>= 1) {
        tsum += __shfl_down(tsum, off);
        psum += __shfl_down(psum, off);
        csum += __shfl_down(csum, off);
    }

    __shared__ float st[4], sp[4], sc[4];
    const int wave = threadIdx.x >> 6;
    const int lane = threadIdx.x & 63;
    if (lane == 0) { st[wave] = tsum; sp[wave] = psum; sc[wave] = csum; }
    __syncthreads();

    if (threadIdx.x == 0) {
        // plain stores to distinct addresses — no contention, no atomics
        part[blockIdx.x]               = sp[0] + sp[1] + sp[2] + sp[3];
        part[nblocks + blockIdx.x]     = st[0] + st[1] + st[2] + st[3];
        part[2 * nblocks + blockIdx.x] = sc[0] + sc[1] + sc[2] + sc[3];
    }
}

__global__ __launch_bounds__(256) void bce_final_kernel(
    const float* __restrict__ part, int nblocks,
    const float* __restrict__ pred, const float* __restrict__ label,
    int n, float* __restrict__ out)
{
    float psum = 0.f, tsum = 0.f, csum = 0.f;
    for (int i = threadIdx.x; i < nblocks; i += NB_THREADS) {
        psum += part[i];
        tsum += part[nblocks + i];
        csum += part[2 * nblocks + i];
    }
#pragma unroll
    for (int off = 32; off > 0; off >>= 1) {
        psum += __shfl_down(psum, off);
        tsum += __shfl_down(tsum, off);
        csum += __shfl_down(csum, off);
    }
    __shared__ float st[4], sp[4], sc[4];
    const int wave = threadIdx.x >> 6;
    const int lane = threadIdx.x & 63;
    if (lane == 0) { st[wave] = tsum; sp[wave] = psum; sc[wave] = csum; }
    __syncthreads();

    if (threadIdx.x == 0) {
        double pos_sum = (double)(sp[0] + sp[1] + sp[2] + sp[3]);
        double tot_sum = (double)(st[0] + st[1] + st[2] + st[3]);
        double cntf    = (double)(sc[0] + sc[1] + sc[2] + sc[3]);

        // scalar tail (n % 4 != 0) — dead for n = 16M
        const int n4 = n >> 2;
        for (int r = (n4 << 2); r < n; ++r) {
            float xi = pred[r], yi = label[r];
            float bce = fmaxf(xi, 0.f) - xi * yi
                      + __logf(1.f + __expf(-fabsf(xi)));
            tot_sum += bce;
            pos_sum += (double)yi * bce;
            cntf    += yi;
        }

        long long num_pos = (long long)(cntf + 0.5);
        long long num_neg = (long long)n - num_pos;
        long long least   = (long long)((double)n * 0.05); // int(n*0.05)
        long long K = 3LL * num_pos;
        if (K < least)   K = least;
        if (K > num_neg) K = num_neg;

        double neg_sum = tot_sum - pos_sum;
        double sel = (num_neg > 0) ? ((double)K * neg_sum / (double)num_neg) : 0.0;
        double denom = (double)num_pos + (double)K;
        out[0] = (float)((denom > 0.0) ? ((pos_sum + sel) / denom) : 0.0);
    }
}

extern "C" void kernel_launch(void* const* d_in, const int* in_sizes, int n_in,
                              void* d_out, int out_size, void* d_ws, size_t ws_size,
                              hipStream_t stream)
{
    const float* pred  = (const float*)d_in[0];
    const float* label = (const float*)d_in[1];
    const int n = in_sizes[0];
    const int n4 = n >> 2;

    // each block covers 1024 float4 = 4096 elements of each array
    int nblocks = (n4 + 1023) / 1024;
    if (nblocks < 1) nblocks = 1;                  // tiny-n safety

    float* part = (float*)d_ws;                    // 3 * nblocks floats

    bce_partial_kernel<<<nblocks, NB_THREADS, 0, stream>>>(pred, label, part,
                                                           n4, nblocks);
    bce_final_kernel<<<1, NB_THREADS, 0, stream>>>(part, nblocks, pred, label,
                                                   n, (float*)d_out);
}